// Round 23
// baseline (92.172 us; speedup 1.0000x reference)
//
#include <hip/hip_runtime.h>
#include <stdint.h>

// Problem constants
#define NN 4096
#define KSEL_S 419430u           // int(4096*4096*0.1) / 4 (4x-subsampled histogram)
#define INV_SQRT_DK 0.17677669529663687f  // 1/sqrt(32)

// Workspace layout (bytes)
#define OFF_QH 0u                     // bf16 Q [4096][128] = 1 MB
#define OFF_KH (1u<<20)               // bf16 K 1 MB
#define OFF_STATS (2u<<20)            // 4096 * float2 = 32 KB
#define OFF_H   (3u<<20)              // 256 partial hists x 1024 u32 = 1 MB
#define OFF_H2  (4u<<20)              // 8 partial hists = 32 KB
#define OFF_ST  ((4u<<20) + 65536u)   // state
#define OFF_MASK (5u<<20)             // dropout bitmask 16.7M bits = 2 MB
#define OFF_SB  (16u<<20)             // bf16 scores 32 MB (only if ws >= 48MB)
#define WS_NEED_B16 (48u<<20)

#define LDB 104                       // padded k-stride (bf16) -> 52 words, 2-way banks

typedef __attribute__((ext_vector_type(8))) short bf16x8;
typedef __attribute__((ext_vector_type(8))) unsigned short u16x8;
typedef __attribute__((ext_vector_type(4))) float f32x4;

static __device__ __forceinline__ short f2bf(float f) {
    unsigned u = __float_as_uint(f);
    unsigned r = (u + 0x7FFFu + ((u >> 16) & 1u)) >> 16;   // RNE
    return (short)r;
}
static __device__ __forceinline__ float bf2f(short h) {
    return __uint_as_float(((unsigned)(unsigned short)h) << 16);
}

// ---------------------------------------------------------------------------
// 1) HETEROGENEOUS proj + mask, SINGLE-BUFFERED proj staging.
//    LDS 53 -> 26.6 KB = 6 blocks/CU, doubling the mask blocks' streaming
//    occupancy (R22 diagnosis: mask waves were LDS-allocation-capped at
//    3 blocks/CU -> 1.45 TB/s). Proj stage/compute serialization is hidden
//    by the 6-deep block interleave. Blocks 0..511: proj (32-row tiles).
//    Blocks 512..2559: u->bitmask.
// ---------------------------------------------------------------------------
__global__ __launch_bounds__(256) void projmask_kernel(
    const float* __restrict__ x, const float* __restrict__ WQ,
    const float* __restrict__ WK,
    short* __restrict__ Qh, short* __restrict__ Kh,
    const float4* __restrict__ u4, unsigned* __restrict__ maskw)
{
    __shared__ short Ah[32 * LDB];
    __shared__ short Al[32 * LDB];
    __shared__ short Bl[64 * LDB];
    const int bxg = blockIdx.x;
    const int tid = threadIdx.x;

    if (bxg >= 512) {
        // ---- mask blocks: one bitmask word per thread ----
        const unsigned word = (unsigned)(bxg - 512) * 256 + tid;
        const float4* __restrict__ up = u4 + (size_t)word * 8;
        unsigned m = 0;
#pragma unroll
        for (int j = 0; j < 8; ++j) {
            float4 a = up[j];
            m |= (a.x >= 0.1f ? 1u : 0u) << (4 * j);
            m |= (a.y >= 0.1f ? 2u : 0u) << (4 * j);
            m |= (a.z >= 0.1f ? 4u : 0u) << (4 * j);
            m |= (a.w >= 0.1f ? 8u : 0u) << (4 * j);
        }
        maskw[word] = m;
        return;
    }

    // ---- proj blocks: C[32 rows x 64 cols(Q32|K32)] for one b ----
    const int b   = bxg >> 7;
    const int n0  = (bxg & 127) << 5;
    const int l   = tid & 63;
    const int w   = __builtin_amdgcn_readfirstlane(tid >> 6);  // 0..3
    const int lr  = l & 15;
    const int kg  = (l >> 4) * 8;
    const int rw  = (w >> 1) << 4;     // wave row-strip: 0 or 16
    const int cw  = (w & 1) << 5;      // wave col-strip: 0 or 32

    f32x4 acc[2];
    acc[0] = (f32x4){0.f, 0.f, 0.f, 0.f};
    acc[1] = (f32x4){0.f, 0.f, 0.f, 0.f};

    auto STAGE = [&](int c) {
        // x: 8 f x 32 rows x 3 float4 = 768 slots, 3/thread
#pragma unroll
        for (int j = 0; j < 3; ++j) {
            const int s   = tid + (j << 8);
            const int f_l = s / 96;
            const int rem = s - f_l * 96;
            const int r   = rem / 3;
            const int t4  = rem - r * 3;            // 0,1,2 -> t offset 0,4,8
            float4 v = *(const float4*)(x + (size_t)b * 3145728
                                          + (size_t)(c * 8 + f_l) * 49152
                                          + (size_t)(n0 + r) * 12 + t4 * 4);
            const int kl = f_l * 12 + t4 * 4;
            short4 hi, lo;
            hi.x = f2bf(v.x); lo.x = f2bf(v.x - bf2f(hi.x));
            hi.y = f2bf(v.y); lo.y = f2bf(v.y - bf2f(hi.y));
            hi.z = f2bf(v.z); lo.z = f2bf(v.z - bf2f(hi.z));
            hi.w = f2bf(v.w); lo.w = f2bf(v.w - bf2f(hi.w));
            *(short4*)&Ah[r * LDB + kl] = hi;
            *(short4*)&Al[r * LDB + kl] = lo;
        }
        // W: 2 mats x 96 k x 8 col4 = 1536 slots, 6/thread; split at 768
#pragma unroll
        for (int j = 0; j < 6; ++j) {
            const int s   = tid + (j << 8);
            const int qk  = (s >= 768) ? 1 : 0;
            const int rem = s - qk * 768;
            const int kr  = rem >> 3;                // 0..95
            const int c4  = rem & 7;
            const int t   = kr % 12;
            const int f_l = kr / 12;
            const float* __restrict__ Wp = qk ? WK : WQ;
            float4 wv = *(const float4*)(Wp + (size_t)(t * 64 + c * 8 + f_l) * 32 + (c4 << 2));
            const int kl = f_l * 12 + t;
            const int col = (qk << 5) + (c4 << 2);
            Bl[(col + 0) * LDB + kl] = f2bf(wv.x);
            Bl[(col + 1) * LDB + kl] = f2bf(wv.y);
            Bl[(col + 2) * LDB + kl] = f2bf(wv.z);
            Bl[(col + 3) * LDB + kl] = f2bf(wv.w);
        }
    };

#pragma unroll 1
    for (int c = 0; c < 8; ++c) {
        if (c) __syncthreads();          // prior chunk's compute done reading
        STAGE(c);
        __syncthreads();
#pragma unroll
        for (int ks = 0; ks < 3; ++ks) {
            const int ko = ks * 32 + kg;
            bf16x8 ah = *(const bf16x8*)&Ah[(rw + lr) * LDB + ko];
            bf16x8 al = *(const bf16x8*)&Al[(rw + lr) * LDB + ko];
#pragma unroll
            for (int j = 0; j < 2; ++j) {
                bf16x8 bb = *(const bf16x8*)&Bl[(cw + j * 16 + lr) * LDB + ko];
                acc[j] = __builtin_amdgcn_mfma_f32_16x16x32_bf16(ah, bb, acc[j], 0, 0, 0);
                acc[j] = __builtin_amdgcn_mfma_f32_16x16x32_bf16(al, bb, acc[j], 0, 0, 0);
            }
        }
    }

    // C/D mapping (m89-verified): col = lane&15, row = (lane>>4)*4 + reg
#pragma unroll
    for (int j = 0; j < 2; ++j) {
        const int col = cw + j * 16 + lr;
#pragma unroll
        for (int r = 0; r < 4; ++r) {
            const int row = n0 + rw + (l >> 4) * 4 + r;
            if (col < 32)
                Qh[(size_t)row * 128 + (b << 5) + col] = f2bf(acc[j][r] * INV_SQRT_DK);
            else
                Kh[(size_t)row * 128 + (b << 5) + (col - 32)] = f2bf(acc[j][r]);
        }
    }
}

// ---------------------------------------------------------------------------
// 2) S = Q @ K^T via MFMA 16x16x32 bf16 (clean R14 form).
// ---------------------------------------------------------------------------
template<bool B16>
__global__ __launch_bounds__(256, 3) void gemm_kernel(
    const short* __restrict__ Qh, const short* __restrict__ Kh, void* Sv)
{
    const int bi = blockIdx.x >> 5, bj = blockIdx.x & 31;
    const int tid = threadIdx.x;
    const int w = tid >> 6, l = tid & 63;
    const int m0 = bi * 128 + (w >> 1) * 64;
    const int n0 = bj * 128 + (w & 1) * 64;
    const int lr = l & 15;
    const int kg = (l >> 4) * 8;

    f32x4 acc[4][4];
#pragma unroll
    for (int i = 0; i < 4; ++i)
#pragma unroll
        for (int j = 0; j < 4; ++j) acc[i][j] = (f32x4){0.f, 0.f, 0.f, 0.f};

    bf16x8 aA[4], bA[4], aB[4], bB[4];

    auto LD = [&](bf16x8* A, bf16x8* B, int k0) {
#pragma unroll
        for (int i = 0; i < 4; ++i) {
            A[i] = *(const bf16x8*)(Qh + (size_t)(m0 + i * 16 + lr) * 128 + k0 + kg);
            B[i] = *(const bf16x8*)(Kh + (size_t)(n0 + i * 16 + lr) * 128 + k0 + kg);
        }
    };
    auto DOMFMA = [&](bf16x8* A, bf16x8* B) {
#pragma unroll
        for (int i = 0; i < 4; ++i)
#pragma unroll
            for (int j = 0; j < 4; ++j)
                acc[i][j] = __builtin_amdgcn_mfma_f32_16x16x32_bf16(A[i], B[j], acc[i][j], 0, 0, 0);
    };

    LD(aA, bA, 0);
    LD(aB, bB, 32);
    DOMFMA(aA, bA);  LD(aA, bA, 64);
    DOMFMA(aB, bB);  LD(aB, bB, 96);
    DOMFMA(aA, bA);
    DOMFMA(aB, bB);

    // C/D mapping (m89-verified): col = lane&15, row = (lane>>4)*4 + reg
#pragma unroll
    for (int i = 0; i < 4; ++i) {
        int rowb = m0 + i * 16 + (l >> 4) * 4;
#pragma unroll
        for (int j = 0; j < 4; ++j) {
            int col = n0 + j * 16 + (l & 15);
#pragma unroll
            for (int r = 0; r < 4; ++r) {
                if constexpr (B16)
                    ((unsigned short*)Sv)[(size_t)(rowb + r) * NN + col] =
                        (unsigned short)f2bf(acc[i][j][r]);
                else
                    ((float*)Sv)[(size_t)(rowb + r) * NN + col] = acc[i][j][r];
            }
        }
    }
}

// ---------------------------------------------------------------------------
// 3) Row stats + SUBSAMPLED histogram, single pass, no max subtraction.
// ---------------------------------------------------------------------------
template<bool B16>
__global__ __launch_bounds__(512) void histstat_kernel(
    const void* __restrict__ Sv, float2* __restrict__ stats,
    unsigned* __restrict__ gh)
{
    __shared__ unsigned h[1024];
    const int tid = threadIdx.x;
    const int l = tid & 63;
    const int w = tid >> 6;

    for (int i = tid; i < 1024; i += 512) h[i] = 0;
    __syncthreads();

#pragma unroll
    for (int r = 0; r < 2; ++r) {
        const int row = (blockIdx.x << 4) + (r << 3) + w;

        float v[64];
        if constexpr (B16) {
            const u16x8* rp = (const u16x8*)((const unsigned short*)Sv + (size_t)row * NN);
#pragma unroll
            for (int j = 0; j < 8; ++j) {
                u16x8 e = rp[l + (j << 6)];
#pragma unroll
                for (int i = 0; i < 8; ++i) v[j * 8 + i] = bf2f((short)e[i]);
            }
        } else {
            const float4* rp = (const float4*)((const float*)Sv + (size_t)row * NN);
#pragma unroll
            for (int j = 0; j < 16; ++j) {
                float4 t = rp[l + (j << 6)];
                v[j * 4 + 0] = t.x; v[j * 4 + 1] = t.y;
                v[j * 4 + 2] = t.z; v[j * 4 + 3] = t.w;
            }
        }

        float s = 0.f;
#pragma unroll
        for (int j = 0; j < 64; ++j) { v[j] = __expf(v[j]); s += v[j]; }
#pragma unroll
        for (int off = 32; off; off >>= 1) s += __shfl_xor(s, off);
        const float inv = 1.0f / s;
        if (l == 0) stats[row] = make_float2(0.f, inv);

        // subsampled histogram: 1/4 of elements
        if constexpr (B16) {
#pragma unroll
            for (int jj = 0; jj < 2; ++jj) {
                const int base = jj * 32;
#pragma unroll
                for (int c = 0; c < 8; ++c) {
                    int b0 = min(max((int)(__float_as_uint(v[base + c] * inv) >> 16) - 0x3780, 0), 1023);
                    atomicAdd(&h[b0], 1u);
                }
            }
        } else {
#pragma unroll
            for (int jj = 0; jj < 4; ++jj) {
                const int base = jj * 16;
#pragma unroll
                for (int c = 0; c < 4; ++c) {
                    int b0 = min(max((int)(__float_as_uint(v[base + c] * inv) >> 16) - 0x3780, 0), 1023);
                    atomicAdd(&h[b0], 1u);
                }
            }
        }
    }

    __syncthreads();
    unsigned* dst = gh + ((unsigned)blockIdx.x << 10);
    for (int i = tid; i < 1024; i += 512) dst[i] = h[i];   // full overwrite
}

// ---------------------------------------------------------------------------
// 4a) Pre-reduce 256 partials -> 8.   4b) Final reduce + suffix-scan.
// ---------------------------------------------------------------------------
__global__ __launch_bounds__(1024) void reduce_kernel(
    const unsigned* __restrict__ gh, unsigned* __restrict__ gh2)
{
    const int t = threadIdx.x, b = blockIdx.x;
    unsigned s = 0;
    for (int p = 0; p < 32; ++p) s += gh[((unsigned)(b * 32 + p) << 10) + t];
    gh2[((unsigned)b << 10) + t] = s;
}

__global__ __launch_bounds__(1024) void scan_kernel(
    const unsigned* __restrict__ gh2, unsigned* st)
{
    __shared__ unsigned P[1024];
    const int t = threadIdx.x;
    unsigned s = 0;
#pragma unroll
    for (int p = 0; p < 8; ++p) s += gh2[(p << 10) + t];
    P[t] = s;
    __syncthreads();
    for (int off = 1; off < 1024; off <<= 1) {
        unsigned v = P[t] + ((t + off < 1024) ? P[t + off] : 0u);
        __syncthreads();
        P[t] = v;
        __syncthreads();
    }
    if (P[t] >= KSEL_S && (t == 1023 || P[t + 1] < KSEL_S))
        st[2] = (0x3780u + (unsigned)t) << 16;   // lower edge of selected bin
}

// ---------------------------------------------------------------------------
// 5) Final: recompute p; threshold -> keep; else dropout via 1-bit mask.
// ---------------------------------------------------------------------------
template<bool B16>
__global__ __launch_bounds__(256) void final_kernel(
    const void* __restrict__ Sv, float* __restrict__ out,
    const unsigned* __restrict__ maskw,
    const float2* __restrict__ stats, const unsigned* __restrict__ st)
{
    const int row = blockIdx.x;
    const int tid = threadIdx.x;
    const float thr = __uint_as_float(st[2]);
    const float2 stt = stats[row];
    float4* o4 = (float4*)(out + (size_t)row * NN);
    const unsigned* mw = maskw + (size_t)row * 128;

    float4 sv[4];
    unsigned wv[4];

    if constexpr (B16) {
        const ushort4* S4 = (const ushort4*)((const unsigned short*)Sv + (size_t)row * NN);
        ushort4 sraw[4];
#pragma unroll
        for (int j = 0; j < 4; ++j) sraw[j] = S4[tid + (j << 8)];
#pragma unroll
        for (int j = 0; j < 4; ++j) wv[j] = mw[(tid >> 3) + (j << 5)];
#pragma unroll
        for (int j = 0; j < 4; ++j) {
            sv[j].x = bf2f((short)sraw[j].x); sv[j].y = bf2f((short)sraw[j].y);
            sv[j].z = bf2f((short)sraw[j].z); sv[j].w = bf2f((short)sraw[j].w);
        }
    } else {
        const float4* S4 = (const float4*)((const float*)Sv + (size_t)row * NN);
#pragma unroll
        for (int j = 0; j < 4; ++j) sv[j] = S4[tid + (j << 8)];
#pragma unroll
        for (int j = 0; j < 4; ++j) wv[j] = mw[(tid >> 3) + (j << 5)];
    }

    const unsigned sh = (tid & 7) << 2;
#pragma unroll
    for (int j = 0; j < 4; ++j) {
        const unsigned bits = (wv[j] >> sh) & 0xFu;
        float4 o;
        float p;
        p = __expf(sv[j].x - stt.x) * stt.y;
        o.x = (p >= thr) ? p : ((bits & 1u) ? p * (1.0f / 0.9f) : 0.0f);
        p = __expf(sv[j].y - stt.x) * stt.y;
        o.y = (p >= thr) ? p : ((bits & 2u) ? p * (1.0f / 0.9f) : 0.0f);
        p = __expf(sv[j].z - stt.x) * stt.y;
        o.z = (p >= thr) ? p : ((bits & 4u) ? p * (1.0f / 0.9f) : 0.0f);
        p = __expf(sv[j].w - stt.x) * stt.y;
        o.w = (p >= thr) ? p : ((bits & 8u) ? p * (1.0f / 0.9f) : 0.0f);
        o4[tid + (j << 8)] = o;
    }
}

extern "C" void kernel_launch(void* const* d_in, const int* in_sizes, int n_in,
                              void* d_out, int out_size, void* d_ws, size_t ws_size,
                              hipStream_t stream)
{
    const float* x  = (const float*)d_in[0];
    const float* WQ = (const float*)d_in[1];
    const float* WK = (const float*)d_in[2];
    const float* du = (const float*)d_in[3];
    float* out = (float*)d_out;
    char* ws = (char*)d_ws;

    short* Qh = (short*)(ws + OFF_QH);
    short* Kh = (short*)(ws + OFF_KH);
    float2* stats = (float2*)(ws + OFF_STATS);
    unsigned* hist = (unsigned*)(ws + OFF_H);
    unsigned* gh2  = (unsigned*)(ws + OFF_H2);
    unsigned* st   = (unsigned*)(ws + OFF_ST);
    unsigned* mask = (unsigned*)(ws + OFF_MASK);

    // heterogeneous: blocks 0..511 proj (single-buffered), 512..2559 mask
    projmask_kernel<<<2560, 256, 0, stream>>>(x, WQ, WK, Qh, Kh,
                                              (const float4*)du, mask);

    const bool b16 = (ws_size >= (size_t)WS_NEED_B16);   // fixed per process -> graph-safe
    if (b16) {
        void* Sb = (void*)(ws + OFF_SB);
        gemm_kernel<true><<<1024, 256, 0, stream>>>(Qh, Kh, Sb);
        histstat_kernel<true><<<256, 512, 0, stream>>>(Sb, stats, hist);
        reduce_kernel<<<8, 1024, 0, stream>>>(hist, gh2);
        scan_kernel<<<1, 1024, 0, stream>>>(gh2, st);
        final_kernel<true><<<NN, 256, 0, stream>>>(Sb, out, mask, stats, st);
    } else {
        gemm_kernel<false><<<1024, 256, 0, stream>>>(Qh, Kh, (void*)out);
        histstat_kernel<false><<<256, 512, 0, stream>>>((void*)out, stats, hist);
        reduce_kernel<<<8, 1024, 0, stream>>>(hist, gh2);
        scan_kernel<<<1, 1024, 0, stream>>>(gh2, st);
        final_kernel<false><<<NN, 256, 0, stream>>>((void*)out, out, mask, stats, st);
    }
}

// Round 24
// 78.340 us; speedup vs baseline: 1.1766x; 1.1766x over previous
//
#include <hip/hip_runtime.h>
#include <stdint.h>

// Problem constants
#define NN 4096
#define KSEL_S 419430u           // int(4096*4096*0.1) / 4 (4x-subsampled histogram)
#define INV_SQRT_DK 0.17677669529663687f  // 1/sqrt(32)

// Workspace layout (bytes)
#define OFF_QH 0u                     // bf16 Q [4096][128] = 1 MB
#define OFF_KH (1u<<20)               // bf16 K 1 MB
#define OFF_STATS (2u<<20)            // 4096 * float2 = 32 KB
#define OFF_H   (3u<<20)              // 256 partial hists x 1024 u32 = 1 MB
#define OFF_H2  (4u<<20)              // 8 partial hists = 32 KB
#define OFF_ST  ((4u<<20) + 65536u)   // state
#define OFF_MASK (5u<<20)             // dropout bitmask 16.7M bits = 2 MB
#define OFF_SB  (16u<<20)             // bf16 scores 32 MB (only if ws >= 48MB)
#define WS_NEED_B16 (48u<<20)

#define LDB 104                       // padded k-stride (bf16) -> 52 words, 2-way banks

typedef __attribute__((ext_vector_type(8))) short bf16x8;
typedef __attribute__((ext_vector_type(8))) unsigned short u16x8;
typedef __attribute__((ext_vector_type(4))) float f32x4;

static __device__ __forceinline__ short f2bf(float f) {
    unsigned u = __float_as_uint(f);
    unsigned r = (u + 0x7FFFu + ((u >> 16) & 1u)) >> 16;   // RNE
    return (short)r;
}
static __device__ __forceinline__ float bf2f(short h) {
    return __uint_as_float(((unsigned)(unsigned short)h) << 16);
}

// ---------------------------------------------------------------------------
// 1) HETEROGENEOUS proj + mask (R22 best-known form, double-buffered).
//    Proj tile 32 rows x 64 cols: LDS 53 KB = 3 blocks/CU; 512 proj blocks
//    interleave with 2048 mask blocks. Blocks 0..511: proj. 512..2559: mask.
//    (R23 single-buffer regressed: stage->compute serialization beat the
//    occupancy gain. R21 wave-split regressed: shared barrier/regalloc.)
// ---------------------------------------------------------------------------
__global__ __launch_bounds__(256) void projmask_kernel(
    const float* __restrict__ x, const float* __restrict__ WQ,
    const float* __restrict__ WK,
    short* __restrict__ Qh, short* __restrict__ Kh,
    const float4* __restrict__ u4, unsigned* __restrict__ maskw)
{
    __shared__ short Ah[2][32 * LDB];
    __shared__ short Al[2][32 * LDB];
    __shared__ short Bl[2][64 * LDB];
    const int bxg = blockIdx.x;
    const int tid = threadIdx.x;

    if (bxg >= 512) {
        // ---- mask blocks: one bitmask word per thread ----
        const unsigned word = (unsigned)(bxg - 512) * 256 + tid;
        const float4* __restrict__ up = u4 + (size_t)word * 8;
        unsigned m = 0;
#pragma unroll
        for (int j = 0; j < 8; ++j) {
            float4 a = up[j];
            m |= (a.x >= 0.1f ? 1u : 0u) << (4 * j);
            m |= (a.y >= 0.1f ? 2u : 0u) << (4 * j);
            m |= (a.z >= 0.1f ? 4u : 0u) << (4 * j);
            m |= (a.w >= 0.1f ? 8u : 0u) << (4 * j);
        }
        maskw[word] = m;
        return;
    }

    // ---- proj blocks: C[32 rows x 64 cols(Q32|K32)] for one b ----
    const int b   = bxg >> 7;
    const int n0  = (bxg & 127) << 5;
    const int l   = tid & 63;
    const int w   = __builtin_amdgcn_readfirstlane(tid >> 6);  // 0..3
    const int lr  = l & 15;
    const int kg  = (l >> 4) * 8;
    const int rw  = (w >> 1) << 4;     // wave row-strip: 0 or 16
    const int cw  = (w & 1) << 5;      // wave col-strip: 0 or 32

    f32x4 acc[2];
    acc[0] = (f32x4){0.f, 0.f, 0.f, 0.f};
    acc[1] = (f32x4){0.f, 0.f, 0.f, 0.f};

    auto STAGE = [&](int c, int sbuf) {
        // x: 8 f x 32 rows x 3 float4 = 768 slots, 3/thread
#pragma unroll
        for (int j = 0; j < 3; ++j) {
            const int s   = tid + (j << 8);
            const int f_l = s / 96;
            const int rem = s - f_l * 96;
            const int r   = rem / 3;
            const int t4  = rem - r * 3;            // 0,1,2 -> t offset 0,4,8
            float4 v = *(const float4*)(x + (size_t)b * 3145728
                                          + (size_t)(c * 8 + f_l) * 49152
                                          + (size_t)(n0 + r) * 12 + t4 * 4);
            const int kl = f_l * 12 + t4 * 4;
            short4 hi, lo;
            hi.x = f2bf(v.x); lo.x = f2bf(v.x - bf2f(hi.x));
            hi.y = f2bf(v.y); lo.y = f2bf(v.y - bf2f(hi.y));
            hi.z = f2bf(v.z); lo.z = f2bf(v.z - bf2f(hi.z));
            hi.w = f2bf(v.w); lo.w = f2bf(v.w - bf2f(hi.w));
            *(short4*)&Ah[sbuf][r * LDB + kl] = hi;
            *(short4*)&Al[sbuf][r * LDB + kl] = lo;
        }
        // W: 2 mats x 96 k x 8 col4 = 1536 slots, 6/thread; split at 768
#pragma unroll
        for (int j = 0; j < 6; ++j) {
            const int s   = tid + (j << 8);
            const int qk  = (s >= 768) ? 1 : 0;
            const int rem = s - qk * 768;
            const int kr  = rem >> 3;                // 0..95
            const int c4  = rem & 7;
            const int t   = kr % 12;
            const int f_l = kr / 12;
            const float* __restrict__ Wp = qk ? WK : WQ;
            float4 wv = *(const float4*)(Wp + (size_t)(t * 64 + c * 8 + f_l) * 32 + (c4 << 2));
            const int kl = f_l * 12 + t;
            const int col = (qk << 5) + (c4 << 2);
            Bl[sbuf][(col + 0) * LDB + kl] = f2bf(wv.x);
            Bl[sbuf][(col + 1) * LDB + kl] = f2bf(wv.y);
            Bl[sbuf][(col + 2) * LDB + kl] = f2bf(wv.z);
            Bl[sbuf][(col + 3) * LDB + kl] = f2bf(wv.w);
        }
    };

    STAGE(0, 0);
    int buf = 0;
#pragma unroll 1
    for (int c = 0; c < 8; ++c) {
        __syncthreads();
        if (c < 7) STAGE(c + 1, buf ^ 1);
#pragma unroll
        for (int ks = 0; ks < 3; ++ks) {
            const int ko = ks * 32 + kg;
            bf16x8 ah = *(const bf16x8*)&Ah[buf][(rw + lr) * LDB + ko];
            bf16x8 al = *(const bf16x8*)&Al[buf][(rw + lr) * LDB + ko];
#pragma unroll
            for (int j = 0; j < 2; ++j) {
                bf16x8 bb = *(const bf16x8*)&Bl[buf][(cw + j * 16 + lr) * LDB + ko];
                acc[j] = __builtin_amdgcn_mfma_f32_16x16x32_bf16(ah, bb, acc[j], 0, 0, 0);
                acc[j] = __builtin_amdgcn_mfma_f32_16x16x32_bf16(al, bb, acc[j], 0, 0, 0);
            }
        }
        buf ^= 1;
    }

    // C/D mapping (m89-verified): col = lane&15, row = (lane>>4)*4 + reg
#pragma unroll
    for (int j = 0; j < 2; ++j) {
        const int col = cw + j * 16 + lr;
#pragma unroll
        for (int r = 0; r < 4; ++r) {
            const int row = n0 + rw + (l >> 4) * 4 + r;
            if (col < 32)
                Qh[(size_t)row * 128 + (b << 5) + col] = f2bf(acc[j][r] * INV_SQRT_DK);
            else
                Kh[(size_t)row * 128 + (b << 5) + (col - 32)] = f2bf(acc[j][r]);
        }
    }
}

// ---------------------------------------------------------------------------
// 2) S = Q @ K^T via MFMA 16x16x32 bf16 (clean R14 form).
// ---------------------------------------------------------------------------
template<bool B16>
__global__ __launch_bounds__(256, 3) void gemm_kernel(
    const short* __restrict__ Qh, const short* __restrict__ Kh, void* Sv)
{
    const int bi = blockIdx.x >> 5, bj = blockIdx.x & 31;
    const int tid = threadIdx.x;
    const int w = tid >> 6, l = tid & 63;
    const int m0 = bi * 128 + (w >> 1) * 64;
    const int n0 = bj * 128 + (w & 1) * 64;
    const int lr = l & 15;
    const int kg = (l >> 4) * 8;

    f32x4 acc[4][4];
#pragma unroll
    for (int i = 0; i < 4; ++i)
#pragma unroll
        for (int j = 0; j < 4; ++j) acc[i][j] = (f32x4){0.f, 0.f, 0.f, 0.f};

    bf16x8 aA[4], bA[4], aB[4], bB[4];

    auto LD = [&](bf16x8* A, bf16x8* B, int k0) {
#pragma unroll
        for (int i = 0; i < 4; ++i) {
            A[i] = *(const bf16x8*)(Qh + (size_t)(m0 + i * 16 + lr) * 128 + k0 + kg);
            B[i] = *(const bf16x8*)(Kh + (size_t)(n0 + i * 16 + lr) * 128 + k0 + kg);
        }
    };
    auto DOMFMA = [&](bf16x8* A, bf16x8* B) {
#pragma unroll
        for (int i = 0; i < 4; ++i)
#pragma unroll
            for (int j = 0; j < 4; ++j)
                acc[i][j] = __builtin_amdgcn_mfma_f32_16x16x32_bf16(A[i], B[j], acc[i][j], 0, 0, 0);
    };

    LD(aA, bA, 0);
    LD(aB, bB, 32);
    DOMFMA(aA, bA);  LD(aA, bA, 64);
    DOMFMA(aB, bB);  LD(aB, bB, 96);
    DOMFMA(aA, bA);
    DOMFMA(aB, bB);

    // C/D mapping (m89-verified): col = lane&15, row = (lane>>4)*4 + reg
#pragma unroll
    for (int i = 0; i < 4; ++i) {
        int rowb = m0 + i * 16 + (l >> 4) * 4;
#pragma unroll
        for (int j = 0; j < 4; ++j) {
            int col = n0 + j * 16 + (l & 15);
#pragma unroll
            for (int r = 0; r < 4; ++r) {
                if constexpr (B16)
                    ((unsigned short*)Sv)[(size_t)(rowb + r) * NN + col] =
                        (unsigned short)f2bf(acc[i][j][r]);
                else
                    ((float*)Sv)[(size_t)(rowb + r) * NN + col] = acc[i][j][r];
            }
        }
    }
}

// ---------------------------------------------------------------------------
// 3) Row stats + SUBSAMPLED histogram, single pass, no max subtraction.
// ---------------------------------------------------------------------------
template<bool B16>
__global__ __launch_bounds__(512) void histstat_kernel(
    const void* __restrict__ Sv, float2* __restrict__ stats,
    unsigned* __restrict__ gh)
{
    __shared__ unsigned h[1024];
    const int tid = threadIdx.x;
    const int l = tid & 63;
    const int w = tid >> 6;

    for (int i = tid; i < 1024; i += 512) h[i] = 0;
    __syncthreads();

#pragma unroll
    for (int r = 0; r < 2; ++r) {
        const int row = (blockIdx.x << 4) + (r << 3) + w;

        float v[64];
        if constexpr (B16) {
            const u16x8* rp = (const u16x8*)((const unsigned short*)Sv + (size_t)row * NN);
#pragma unroll
            for (int j = 0; j < 8; ++j) {
                u16x8 e = rp[l + (j << 6)];
#pragma unroll
                for (int i = 0; i < 8; ++i) v[j * 8 + i] = bf2f((short)e[i]);
            }
        } else {
            const float4* rp = (const float4*)((const float*)Sv + (size_t)row * NN);
#pragma unroll
            for (int j = 0; j < 16; ++j) {
                float4 t = rp[l + (j << 6)];
                v[j * 4 + 0] = t.x; v[j * 4 + 1] = t.y;
                v[j * 4 + 2] = t.z; v[j * 4 + 3] = t.w;
            }
        }

        float s = 0.f;
#pragma unroll
        for (int j = 0; j < 64; ++j) { v[j] = __expf(v[j]); s += v[j]; }
#pragma unroll
        for (int off = 32; off; off >>= 1) s += __shfl_xor(s, off);
        const float inv = 1.0f / s;
        if (l == 0) stats[row] = make_float2(0.f, inv);

        // subsampled histogram: 1/4 of elements
        if constexpr (B16) {
#pragma unroll
            for (int jj = 0; jj < 2; ++jj) {
                const int base = jj * 32;
#pragma unroll
                for (int c = 0; c < 8; ++c) {
                    int b0 = min(max((int)(__float_as_uint(v[base + c] * inv) >> 16) - 0x3780, 0), 1023);
                    atomicAdd(&h[b0], 1u);
                }
            }
        } else {
#pragma unroll
            for (int jj = 0; jj < 4; ++jj) {
                const int base = jj * 16;
#pragma unroll
                for (int c = 0; c < 4; ++c) {
                    int b0 = min(max((int)(__float_as_uint(v[base + c] * inv) >> 16) - 0x3780, 0), 1023);
                    atomicAdd(&h[b0], 1u);
                }
            }
        }
    }

    __syncthreads();
    unsigned* dst = gh + ((unsigned)blockIdx.x << 10);
    for (int i = tid; i < 1024; i += 512) dst[i] = h[i];   // full overwrite
}

// ---------------------------------------------------------------------------
// 4a) Pre-reduce 256 partials -> 8.   4b) Final reduce + suffix-scan.
// ---------------------------------------------------------------------------
__global__ __launch_bounds__(1024) void reduce_kernel(
    const unsigned* __restrict__ gh, unsigned* __restrict__ gh2)
{
    const int t = threadIdx.x, b = blockIdx.x;
    unsigned s = 0;
    for (int p = 0; p < 32; ++p) s += gh[((unsigned)(b * 32 + p) << 10) + t];
    gh2[((unsigned)b << 10) + t] = s;
}

__global__ __launch_bounds__(1024) void scan_kernel(
    const unsigned* __restrict__ gh2, unsigned* st)
{
    __shared__ unsigned P[1024];
    const int t = threadIdx.x;
    unsigned s = 0;
#pragma unroll
    for (int p = 0; p < 8; ++p) s += gh2[(p << 10) + t];
    P[t] = s;
    __syncthreads();
    for (int off = 1; off < 1024; off <<= 1) {
        unsigned v = P[t] + ((t + off < 1024) ? P[t + off] : 0u);
        __syncthreads();
        P[t] = v;
        __syncthreads();
    }
    if (P[t] >= KSEL_S && (t == 1023 || P[t + 1] < KSEL_S))
        st[2] = (0x3780u + (unsigned)t) << 16;   // lower edge of selected bin
}

// ---------------------------------------------------------------------------
// 5) Final: recompute p; threshold -> keep; else dropout via 1-bit mask.
// ---------------------------------------------------------------------------
template<bool B16>
__global__ __launch_bounds__(256) void final_kernel(
    const void* __restrict__ Sv, float* __restrict__ out,
    const unsigned* __restrict__ maskw,
    const float2* __restrict__ stats, const unsigned* __restrict__ st)
{
    const int row = blockIdx.x;
    const int tid = threadIdx.x;
    const float thr = __uint_as_float(st[2]);
    const float2 stt = stats[row];
    float4* o4 = (float4*)(out + (size_t)row * NN);
    const unsigned* mw = maskw + (size_t)row * 128;

    float4 sv[4];
    unsigned wv[4];

    if constexpr (B16) {
        const ushort4* S4 = (const ushort4*)((const unsigned short*)Sv + (size_t)row * NN);
        ushort4 sraw[4];
#pragma unroll
        for (int j = 0; j < 4; ++j) sraw[j] = S4[tid + (j << 8)];
#pragma unroll
        for (int j = 0; j < 4; ++j) wv[j] = mw[(tid >> 3) + (j << 5)];
#pragma unroll
        for (int j = 0; j < 4; ++j) {
            sv[j].x = bf2f((short)sraw[j].x); sv[j].y = bf2f((short)sraw[j].y);
            sv[j].z = bf2f((short)sraw[j].z); sv[j].w = bf2f((short)sraw[j].w);
        }
    } else {
        const float4* S4 = (const float4*)((const float*)Sv + (size_t)row * NN);
#pragma unroll
        for (int j = 0; j < 4; ++j) sv[j] = S4[tid + (j << 8)];
#pragma unroll
        for (int j = 0; j < 4; ++j) wv[j] = mw[(tid >> 3) + (j << 5)];
    }

    const unsigned sh = (tid & 7) << 2;
#pragma unroll
    for (int j = 0; j < 4; ++j) {
        const unsigned bits = (wv[j] >> sh) & 0xFu;
        float4 o;
        float p;
        p = __expf(sv[j].x - stt.x) * stt.y;
        o.x = (p >= thr) ? p : ((bits & 1u) ? p * (1.0f / 0.9f) : 0.0f);
        p = __expf(sv[j].y - stt.x) * stt.y;
        o.y = (p >= thr) ? p : ((bits & 2u) ? p * (1.0f / 0.9f) : 0.0f);
        p = __expf(sv[j].z - stt.x) * stt.y;
        o.z = (p >= thr) ? p : ((bits & 4u) ? p * (1.0f / 0.9f) : 0.0f);
        p = __expf(sv[j].w - stt.x) * stt.y;
        o.w = (p >= thr) ? p : ((bits & 8u) ? p * (1.0f / 0.9f) : 0.0f);
        o4[tid + (j << 8)] = o;
    }
}

extern "C" void kernel_launch(void* const* d_in, const int* in_sizes, int n_in,
                              void* d_out, int out_size, void* d_ws, size_t ws_size,
                              hipStream_t stream)
{
    const float* x  = (const float*)d_in[0];
    const float* WQ = (const float*)d_in[1];
    const float* WK = (const float*)d_in[2];
    const float* du = (const float*)d_in[3];
    float* out = (float*)d_out;
    char* ws = (char*)d_ws;

    short* Qh = (short*)(ws + OFF_QH);
    short* Kh = (short*)(ws + OFF_KH);
    float2* stats = (float2*)(ws + OFF_STATS);
    unsigned* hist = (unsigned*)(ws + OFF_H);
    unsigned* gh2  = (unsigned*)(ws + OFF_H2);
    unsigned* st   = (unsigned*)(ws + OFF_ST);
    unsigned* mask = (unsigned*)(ws + OFF_MASK);

    // heterogeneous: blocks 0..511 proj (32-row tiles, dbuf), 512..2559 mask
    projmask_kernel<<<2560, 256, 0, stream>>>(x, WQ, WK, Qh, Kh,
                                              (const float4*)du, mask);

    const bool b16 = (ws_size >= (size_t)WS_NEED_B16);   // fixed per process -> graph-safe
    if (b16) {
        void* Sb = (void*)(ws + OFF_SB);
        gemm_kernel<true><<<1024, 256, 0, stream>>>(Qh, Kh, Sb);
        histstat_kernel<true><<<256, 512, 0, stream>>>(Sb, stats, hist);
        reduce_kernel<<<8, 1024, 0, stream>>>(hist, gh2);
        scan_kernel<<<1, 1024, 0, stream>>>(gh2, st);
        final_kernel<true><<<NN, 256, 0, stream>>>(Sb, out, mask, stats, st);
    } else {
        gemm_kernel<false><<<1024, 256, 0, stream>>>(Qh, Kh, (void*)out);
        histstat_kernel<false><<<256, 512, 0, stream>>>((void*)out, stats, hist);
        reduce_kernel<<<8, 1024, 0, stream>>>(hist, gh2);
        scan_kernel<<<1, 1024, 0, stream>>>(gh2, st);
        final_kernel<false><<<NN, 256, 0, stream>>>((void*)out, out, mask, stats, st);
    }
}